// Round 8
// baseline (279.572 us; speedup 1.0000x reference)
//
#include <hip/hip_runtime.h>
#include <hip/hip_bf16.h>

#define N_NODES 20000
#define B 4
#define H 128
#define I_DIM 64
#define E_MAX 320000
#define CAP 64              // padded CSR row capacity (in-deg ~Poisson(16); P(>63) ~ e^-40)

typedef __attribute__((ext_vector_type(8))) short short8;   // 8 bf16 = 4 VGPR (MFMA A/B frag)
typedef __attribute__((ext_vector_type(4))) float float4v;  // MFMA C/D frag

// ---- all scratch in module-static device globals (no d_ws dependence) ----
// g_cnt_dst / g_deg_src zeroed by fused_kernel (own-nodes only, end of kernel).
__device__ int   g_cnt_dst[N_NODES];        // atomic cursor == final in-degree
__device__ int   g_deg_src[N_NODES];        // out-degree
__device__ int   g_csr[N_NODES * CAP];      // padded CSR: row n at n*CAP
__device__ __align__(16) float g_xg[4 * B * H];   // layout: [(b*H+h)*4 + gate]
// batch-interleaved bf16 h_prev, PRE-SCALED by dn_src: g_hs[n*H+h]={bf16 h*dn, b=0..3}
__device__ __align__(16) uint2 g_hs[N_NODES * H];
// Wg as bf16 in MFMA B-fragment order: idx=((tn*4+kb)*64+lane)*8+j holds
// Wg[kb*32+(lane>>4)*8+j][tn*16+(lane&15)]  -> per-frag load = 1 coalesced dwordx4
__device__ __align__(16) unsigned short g_wgB[H * H];

// ---- K1: src-degree histogram + xgate + Wg bf16 B-frag pack ----
__global__ __launch_bounds__(256)
void degree_kernel(const int* __restrict__ src, int E, int eb,
                   const float* __restrict__ x,
                   const float* __restrict__ Wi, const float* __restrict__ bi,
                   const float* __restrict__ Wf, const float* __restrict__ bf_,
                   const float* __restrict__ Wo, const float* __restrict__ bo,
                   const float* __restrict__ Wc, const float* __restrict__ bc,
                   const float* __restrict__ Wg) {
    int blk = blockIdx.x;
    int t = threadIdx.x;
    if (blk < eb) {
        int e = blk * 256 + t;
        if (e < E) atomicAdd(&g_deg_src[src[e]], 1);
    } else if (blk < eb + 8) {
        int bid = blk - eb;                       // 0..7
        int g = bid >> 1;                         // gate 0..3
        int b = ((bid & 1) << 1) | (t >> 7);      // batch 0..3
        int h = t & 127;
        const float* W;
        const float* bb;
        switch (g) {
            case 0: W = Wi; bb = bi; break;
            case 1: W = Wf; bb = bf_; break;
            case 2: W = Wo; bb = bo; break;
            default: W = Wc; bb = bc; break;
        }
        float acc = bb[h];
#pragma unroll
        for (int i = 0; i < I_DIM; i++)
            acc += x[b * I_DIM + i] * W[i * H + h];
        g_xg[(b * H + h) * 4 + g] = acc;          // gate-innermost for float4 read
    } else {
        // B-fragment pack: 64 blocks x 256 threads = 16384 = H*H elements
        int i = (blk - eb - 8) * 256 + t;
        int tn = i >> 11;
        int rem = i & 2047;
        int kb = rem >> 9;
        int rem2 = rem & 511;
        int lane = rem2 >> 3;
        int j = rem2 & 7;
        int k  = kb * 32 + (lane >> 4) * 8 + j;
        int nn = tn * 16 + (lane & 15);
        __hip_bfloat16 hv = __float2bfloat16(Wg[k * H + nn]);
        g_wgB[i] = *reinterpret_cast<unsigned short*>(&hv);
    }
}

// ---- K2: pack (dn_src folded into bf16) + padded-CSR place ----
__global__ __launch_bounds__(256)
void mid_kernel(const float* __restrict__ h_prev,
                const int* __restrict__ src, const int* __restrict__ dst, int E) {
    const int PACK_BLKS = (N_NODES * H) / 256;   // 10000, exact
    int blk = blockIdx.x;
    int t = threadIdx.x;

    if (blk < PACK_BLKS) {
        int i = blk * 256 + t;                    // (n*H + h)
        int n = i >> 7;                           // H = 128
        float sc = rsqrtf(fmaxf((float)g_deg_src[n], 1.0f));
        const long stride = (long)N_NODES * H;
        float v0 = h_prev[i] * sc;
        float v1 = h_prev[i + stride] * sc;
        float v2 = h_prev[i + 2 * stride] * sc;
        float v3 = h_prev[i + 3 * stride] * sc;
        __hip_bfloat162 p01 = __float22bfloat162_rn(make_float2(v0, v1));
        __hip_bfloat162 p23 = __float22bfloat162_rn(make_float2(v2, v3));
        uint2 wv;
        wv.x = *reinterpret_cast<unsigned int*>(&p01);
        wv.y = *reinterpret_cast<unsigned int*>(&p23);
        g_hs[i] = wv;
    } else {
        int e = (blk - PACK_BLKS) * 256 + t;
        if (e < E) {
            int d = dst[e];
            int slot = atomicAdd(&g_cnt_dst[d], 1);
            if (slot < CAP) g_csr[(d << 6) + slot] = src[e];
        }
    }
}

__device__ __forceinline__ float fast_sigmoid(float z) {
    return 1.f / (1.f + __expf(-z));
}
__device__ __forceinline__ float fast_tanh(float z) {
    return 1.f - 2.f / (__expf(2.f * z) + 1.f);
}
__device__ __forceinline__ unsigned pack2bf(float lo, float hi) {
    __hip_bfloat162 p = __float22bfloat162_rn(make_float2(lo, hi));
    return *reinterpret_cast<unsigned*>(&p);
}

// ------- K3 fused: WAVE-INDEPENDENT. Each wave owns 4 nodes end-to-end: ------
// gather 4 nodes (16-deep MLP) -> wave-private 16x128 A-tile in LDS ->
// 32 MFMAs (8 N-tiles x 4 K-steps) -> LSTM epilogue. NO __syncthreads.
// A-row r = node_i*4 + batch; C: col=lane&15 -> h-in-tile, row=(lane>>4)*4+reg.
__global__ __launch_bounds__(256)
void fused_kernel(const float* __restrict__ bg,
                  const float* __restrict__ c_prev,
                  float* __restrict__ out_h, float* __restrict__ out_c) {
    int t = threadIdx.x;
    int w = t >> 6;
    int lane = t & 63;
    int q = (blockIdx.x * 4 + w) * 4;          // first of this wave's 4 nodes
    const long stride = (long)N_NODES * H;

    __shared__ int            sbase[4][4 * 64];       // wave-private row bases
    __shared__ unsigned short Atile[4][16][136];      // wave-private A-tiles

    // ---- counts + dn_dst for the 4 nodes (broadcast loads) ----
    int cnt0 = g_cnt_dst[q + 0];
    int cnt1 = g_cnt_dst[q + 1];
    int cnt2 = g_cnt_dst[q + 2];
    int cnt3 = g_cnt_dst[q + 3];
    float dd0 = rsqrtf(fmaxf((float)cnt0, 1.0f)); if (cnt0 > CAP) cnt0 = CAP;
    float dd1 = rsqrtf(fmaxf((float)cnt1, 1.0f)); if (cnt1 > CAP) cnt1 = CAP;
    float dd2 = rsqrtf(fmaxf((float)cnt2, 1.0f)); if (cnt2 > CAP) cnt2 = CAP;
    float dd3 = rsqrtf(fmaxf((float)cnt3, 1.0f)); if (cnt3 > CAP) cnt3 = CAP;

    // ---- stage all 4 nodes' row bases (4 independent coalesced loads) ----
    {
        int s0 = g_csr[((q + 0) << 6) + (lane < cnt0 ? lane : 0)];
        int s1 = g_csr[((q + 1) << 6) + (lane < cnt1 ? lane : 0)];
        int s2 = g_csr[((q + 2) << 6) + (lane < cnt2 ? lane : 0)];
        int s3 = g_csr[((q + 3) << 6) + (lane < cnt3 ? lane : 0)];
        sbase[w][0 * 64 + lane] = s0 << 6;     // uint4-unit row base = s*64
        sbase[w][1 * 64 + lane] = s1 << 6;
        sbase[w][2 * 64 + lane] = s2 << 6;
        sbase[w][3 * 64 + lane] = s3 << 6;
    }

    const uint4* hs4 = reinterpret_cast<const uint4*>(g_hs);
    const int* sb = sbase[w];

#define ACCV(v) { \
        __hip_bfloat162 p; float2 f; \
        p = *reinterpret_cast<__hip_bfloat162*>(&(v).x); f = __bfloat1622float2(p); a0 += f.x; a1 += f.y; \
        p = *reinterpret_cast<__hip_bfloat162*>(&(v).y); f = __bfloat1622float2(p); a2 += f.x; a3 += f.y; \
        p = *reinterpret_cast<__hip_bfloat162*>(&(v).z); f = __bfloat1622float2(p); a4 += f.x; a5 += f.y; \
        p = *reinterpret_cast<__hip_bfloat162*>(&(v).w); f = __bfloat1622float2(p); a6 += f.x; a7 += f.y; }

#define GATHER_NODE(i, cnt, dd) { \
        float a0 = 0.f, a1 = 0.f, a2 = 0.f, a3 = 0.f; \
        float a4 = 0.f, a5 = 0.f, a6 = 0.f, a7 = 0.f; \
        int j = 0; \
        for (; j + 16 <= (cnt); j += 16) { \
            int b0 = sb[(i) * 64 + j];      int b1 = sb[(i) * 64 + j + 1]; \
            int b2 = sb[(i) * 64 + j + 2];  int b3 = sb[(i) * 64 + j + 3]; \
            int b4 = sb[(i) * 64 + j + 4];  int b5 = sb[(i) * 64 + j + 5]; \
            int b6 = sb[(i) * 64 + j + 6];  int b7 = sb[(i) * 64 + j + 7]; \
            int b8 = sb[(i) * 64 + j + 8];  int b9 = sb[(i) * 64 + j + 9]; \
            int b10 = sb[(i) * 64 + j + 10]; int b11 = sb[(i) * 64 + j + 11]; \
            int b12 = sb[(i) * 64 + j + 12]; int b13 = sb[(i) * 64 + j + 13]; \
            int b14 = sb[(i) * 64 + j + 14]; int b15 = sb[(i) * 64 + j + 15]; \
            uint4 v0 = hs4[b0 + lane];   uint4 v1 = hs4[b1 + lane]; \
            uint4 v2 = hs4[b2 + lane];   uint4 v3 = hs4[b3 + lane]; \
            uint4 v4 = hs4[b4 + lane];   uint4 v5 = hs4[b5 + lane]; \
            uint4 v6 = hs4[b6 + lane];   uint4 v7 = hs4[b7 + lane]; \
            uint4 v8 = hs4[b8 + lane];   uint4 v9 = hs4[b9 + lane]; \
            uint4 v10 = hs4[b10 + lane]; uint4 v11 = hs4[b11 + lane]; \
            uint4 v12 = hs4[b12 + lane]; uint4 v13 = hs4[b13 + lane]; \
            uint4 v14 = hs4[b14 + lane]; uint4 v15 = hs4[b15 + lane]; \
            ACCV(v0);  ACCV(v1);  ACCV(v2);  ACCV(v3); \
            ACCV(v4);  ACCV(v5);  ACCV(v6);  ACCV(v7); \
            ACCV(v8);  ACCV(v9);  ACCV(v10); ACCV(v11); \
            ACCV(v12); ACCV(v13); ACCV(v14); ACCV(v15); \
        } \
        for (; j + 4 <= (cnt); j += 4) { \
            int b0 = sb[(i) * 64 + j];     int b1 = sb[(i) * 64 + j + 1]; \
            int b2 = sb[(i) * 64 + j + 2]; int b3 = sb[(i) * 64 + j + 3]; \
            uint4 v0 = hs4[b0 + lane]; uint4 v1 = hs4[b1 + lane]; \
            uint4 v2 = hs4[b2 + lane]; uint4 v3 = hs4[b3 + lane]; \
            ACCV(v0); ACCV(v1); ACCV(v2); ACCV(v3); \
        } \
        for (; j < (cnt); j++) { \
            uint4 v = hs4[sb[(i) * 64 + j] + lane]; \
            ACCV(v); \
        } \
        *reinterpret_cast<unsigned*>(&Atile[w][(i) * 4 + 0][2 * lane]) = pack2bf(a0 * (dd), a4 * (dd)); \
        *reinterpret_cast<unsigned*>(&Atile[w][(i) * 4 + 1][2 * lane]) = pack2bf(a1 * (dd), a5 * (dd)); \
        *reinterpret_cast<unsigned*>(&Atile[w][(i) * 4 + 2][2 * lane]) = pack2bf(a2 * (dd), a6 * (dd)); \
        *reinterpret_cast<unsigned*>(&Atile[w][(i) * 4 + 3][2 * lane]) = pack2bf(a3 * (dd), a7 * (dd)); \
    }

    GATHER_NODE(0, cnt0, dd0);
    GATHER_NODE(1, cnt1, dd1);

    // ---- c_prev prefetch (nontemporal, read-once) hides under nodes 2-3 +
    //      MFMA phase (~1000+ cy of independent work) ----
    int hl = lane & 15;
    long ne = (long)(q + (lane >> 4));
    float cpr[8][4];
#pragma unroll
    for (int tn = 0; tn < 8; tn++) {
        int h = tn * 16 + hl;
#pragma unroll
        for (int jj = 0; jj < 4; jj++)
            cpr[tn][jj] = __builtin_nontemporal_load(
                &c_prev[(long)jj * stride + ne * H + h]);
    }

    GATHER_NODE(2, cnt2, dd2);
    GATHER_NODE(3, cnt3, dd3);
#undef GATHER_NODE
#undef ACCV

    // ---- MFMA: wave-private A-tile, all 8 N-tiles, K=128 in 4 steps ----
    // (compiler inserts lgkmcnt for same-wave Atile write->read ordering)
    int arow = lane & 15;
    int agrp = lane >> 4;
    float4v c[8];
#pragma unroll
    for (int tn = 0; tn < 8; tn++) c[tn] = (float4v){0.f, 0.f, 0.f, 0.f};
#pragma unroll
    for (int kb = 0; kb < 4; kb++) {
        short8 af = *reinterpret_cast<const short8*>(&Atile[w][arow][kb * 32 + agrp * 8]);
#pragma unroll
        for (int tn = 0; tn < 8; tn++) {
            short8 bf = *reinterpret_cast<const short8*>(
                &g_wgB[((tn * 4 + kb) * 64 + lane) * 8]);
            c[tn] = __builtin_amdgcn_mfma_f32_16x16x32_bf16(af, bf, c[tn], 0, 0, 0);
        }
    }

    // ---- epilogue: C (tn, reg jj, lane) -> (node=q+(lane>>4), b=jj, h) ----
    const float4* xg4 = reinterpret_cast<const float4*>(g_xg);
#pragma unroll
    for (int tn = 0; tn < 8; tn++) {
        int h = tn * 16 + hl;
        float bgh = bg[h];
#pragma unroll
        for (int jj = 0; jj < 4; jj++) {
            float gh = c[tn][jj] + bgh;
            float4 xv = xg4[jj * H + h];       // {xi, xf, xo, xc}

            float it = fast_sigmoid(xv.x + gh);
            float ft = fast_sigmoid(xv.y + gh);
            float ot = fast_sigmoid(xv.z + gh);
            float ct = fast_tanh(xv.w + gh);

            float cc = ft * cpr[tn][jj] + it * ct;
            float ho = ot * fast_tanh(cc);

            long idx = (long)jj * stride + ne * H + h;
            __builtin_nontemporal_store(ho, &out_h[idx]);
            __builtin_nontemporal_store(cc, &out_c[idx]);
        }
    }

    // ---- own-node counter zeroing (reads long since consumed; fused never
    //      reads g_deg_src, and g_cnt_dst only for its own nodes) ----
    if (lane < 4) {
        g_cnt_dst[q + lane] = 0;
        g_deg_src[q + lane] = 0;
    }
}

extern "C" void kernel_launch(void* const* d_in, const int* in_sizes, int n_in,
                              void* d_out, int out_size, void* d_ws, size_t ws_size,
                              hipStream_t stream) {
    const float* x      = (const float*)d_in[0];
    const float* h_prev = (const float*)d_in[1];
    const float* c_prev = (const float*)d_in[2];
    const int* src = (const int*)d_in[3];
    const int* dst = (const int*)d_in[4];
    const float* Wi = (const float*)d_in[5];
    const float* bi = (const float*)d_in[6];
    const float* Wf = (const float*)d_in[7];
    const float* bf_ = (const float*)d_in[8];
    const float* Wo = (const float*)d_in[9];
    const float* bo = (const float*)d_in[10];
    const float* Wc = (const float*)d_in[11];
    const float* bc = (const float*)d_in[12];
    const float* Wg = (const float*)d_in[13];
    const float* bg = (const float*)d_in[14];

    int E = in_sizes[3];
    if (E > E_MAX) E = E_MAX;   // static scratch bound (setup fixes E=320000)
    int eb = (E + 255) / 256;
    const int PACK_BLKS = (N_NODES * H) / 256;   // 10000

    degree_kernel<<<eb + 8 + 64, 256, 0, stream>>>(src, E, eb,
        x, Wi, bi, Wf, bf_, Wo, bo, Wc, bc, Wg);
    mid_kernel<<<PACK_BLKS + eb, 256, 0, stream>>>(h_prev, src, dst, E);

    float* out_h = (float*)d_out;
    float* out_c = out_h + (long)B * N_NODES * H;
    fused_kernel<<<N_NODES / 16, 256, 0, stream>>>(bg, c_prev, out_h, out_c);
}